// Round 3
// baseline (618.804 us; speedup 1.0000x reference)
//
#include <hip/hip_runtime.h>
#include <cstdint>
#include <cstddef>

// MultiResHashGrid encode: 1e6 points, 16 levels, 2 feats/level, 2^19 hashmap.
// Output per point: [x,y,z, f(l0,0),f(l0,1), ..., f(l15,0),f(l15,1)] = 35 f32.
//
// R3: level-major two-pass with CHUNK-TILED workspace.
//   ws layout: [chunk][level][256 pts][2 feats]  (2KB per pass1 block,
//   32KB contiguous per pass2 block) -> both passes stream ws sequentially.
//   ws/out stores are non-temporal to keep the L2 for the active hash table.

#define NPTS     1000000
#define NLEV     16
#define TBL_ENT  524288      // 2^19 entries per level
#define BLK      256
#define OUT_PP   35          // floats per point
#define CHUNKS   ((NPTS + BLK - 1) / BLK)   // 3907
#define WS_CHUNK (NLEV * BLK * 2)           // 8192 floats per chunk

// r:  16  22  30  42  58  80  111  153  212  294  406  561  776  1072 1482 2048
// hs: min(r^3, 2^19)
constexpr float    cRes[NLEV] = {16.f, 22.f, 30.f, 42.f, 58.f, 80.f, 111.f, 153.f,
                                 212.f, 294.f, 406.f, 561.f, 776.f, 1072.f, 1482.f, 2048.f};
constexpr uint32_t cHS[NLEV]  = {4096u, 10648u, 27000u, 74088u, 195112u, 512000u,
                                 524288u, 524288u, 524288u, 524288u, 524288u,
                                 524288u, 524288u, 524288u, 524288u, 524288u};

typedef float vfloat4 __attribute__((ext_vector_type(4)));

// ---------------- per-level gather, compile-time level params ----------------

template<int L>
__device__ __forceinline__ void do_level(float px, float py, float pz,
                                         const float* __restrict__ tables,
                                         float& f0, float& f1)
{
    constexpr float    r  = cRes[L];
    constexpr uint32_t hs = cHS[L];
    const float2* __restrict__ tbl =
        reinterpret_cast<const float2*>(tables) + (size_t)L * TBL_ENT;

    const float xs = px * r, ys = py * r, zs = pz * r;
    const int xi = (int)xs, yi = (int)ys, zi = (int)zs;
    const float xf = xs - (float)xi, yf = ys - (float)yi, zf = zs - (float)zi;

    const uint32_t hx0 = (uint32_t)xi;
    const uint32_t hx1 = hx0 + 1u;
    const uint32_t hy0 = (uint32_t)yi * 2654435761u;
    const uint32_t hy1 = hy0 + 2654435761u;
    const uint32_t hz0 = (uint32_t)zi * 805459861u;
    const uint32_t hz1 = hz0 + 805459861u;

    const float wx0 = 1.f - xf, wx1 = xf;
    const float wy0 = 1.f - yf, wy1 = yf;
    const float wz0 = 1.f - zf, wz1 = zf;

    uint32_t hid[8];
    float    w[8];
    #pragma unroll
    for (int c = 0; c < 8; ++c) {
        const uint32_t hxc = (c & 1) ? hx1 : hx0;
        const uint32_t hyc = (c & 2) ? hy1 : hy0;
        const uint32_t hzc = (c & 4) ? hz1 : hz0;
        hid[c] = (hxc ^ hyc ^ hzc) % hs;   // hs compile-time: AND or magic-mul
        const float wxc = (c & 1) ? wx1 : wx0;
        const float wyc = (c & 2) ? wy1 : wy0;
        const float wzc = (c & 4) ? wz1 : wz0;
        w[c] = wxc * wyc * wzc;
    }

    float2 v[8];
    #pragma unroll
    for (int c = 0; c < 8; ++c) v[c] = tbl[hid[c]];

    f0 = 0.f; f1 = 0.f;
    #pragma unroll
    for (int c = 0; c < 8; ++c) {
        f0 = fmaf(w[c], v[c].x, f0);
        f1 = fmaf(w[c], v[c].y, f1);
    }
}

__device__ __forceinline__ void do_level_dispatch(int l, float px, float py, float pz,
                                                  const float* __restrict__ tables,
                                                  float& f0, float& f1)
{
    switch (l) {
        case 0:  do_level<0 >(px, py, pz, tables, f0, f1); break;
        case 1:  do_level<1 >(px, py, pz, tables, f0, f1); break;
        case 2:  do_level<2 >(px, py, pz, tables, f0, f1); break;
        case 3:  do_level<3 >(px, py, pz, tables, f0, f1); break;
        case 4:  do_level<4 >(px, py, pz, tables, f0, f1); break;
        case 5:  do_level<5 >(px, py, pz, tables, f0, f1); break;
        case 6:  do_level<6 >(px, py, pz, tables, f0, f1); break;
        case 7:  do_level<7 >(px, py, pz, tables, f0, f1); break;
        case 8:  do_level<8 >(px, py, pz, tables, f0, f1); break;
        case 9:  do_level<9 >(px, py, pz, tables, f0, f1); break;
        case 10: do_level<10>(px, py, pz, tables, f0, f1); break;
        case 11: do_level<11>(px, py, pz, tables, f0, f1); break;
        case 12: do_level<12>(px, py, pz, tables, f0, f1); break;
        case 13: do_level<13>(px, py, pz, tables, f0, f1); break;
        case 14: do_level<14>(px, py, pz, tables, f0, f1); break;
        default: do_level<15>(px, py, pz, tables, f0, f1); break;
    }
}

// ---------------- Pass 1: per-level gather -> chunk-tiled ws ----------------

__global__ __launch_bounds__(BLK) void hashgrid_pass1(
    const float* __restrict__ x,
    const float* __restrict__ tables,
    float* __restrict__ ws)
{
    const int b = blockIdx.x;
    const int l = b / CHUNKS;          // level (block-uniform)
    const int c = b - l * CHUNKS;      // point chunk
    const int i = c * BLK + threadIdx.x;
    if (i >= NPTS) return;

    const float px = x[3 * i + 0];
    const float py = x[3 * i + 1];
    const float pz = x[3 * i + 2];

    float f0, f1;
    do_level_dispatch(l, px, py, pz, tables, f0, f1);

    // chunk-tiled, coalesced 8B, non-temporal (write-once)
    float2 v2 = make_float2(f0, f1);
    double* dst = reinterpret_cast<double*>(
        ws + (size_t)c * WS_CHUNK + l * (BLK * 2) + threadIdx.x * 2);
    __builtin_nontemporal_store(*reinterpret_cast<double*>(&v2), dst);
}

// ---------------- Pass 2: assemble rows, fully streaming ----------------

__global__ __launch_bounds__(BLK) void hashgrid_pass2(
    const float* __restrict__ x,
    const float* __restrict__ ws,
    float* __restrict__ out)
{
    __shared__ float smem[BLK * OUT_PP];   // 35840 B

    const int t = threadIdx.x;
    const int c = blockIdx.x;
    const int i = c * BLK + t;
    const bool active = (i < NPTS);

    const float* __restrict__ wsc = ws + (size_t)c * WS_CHUNK;

    if (active) {
        smem[t * OUT_PP + 0] = x[3 * i + 0];
        smem[t * OUT_PP + 1] = x[3 * i + 1];
        smem[t * OUT_PP + 2] = x[3 * i + 2];
    }
    #pragma unroll
    for (int l = 0; l < NLEV; ++l) {
        // contiguous within the chunk: 512B per wave per level
        const float2 v = reinterpret_cast<const float2*>(wsc + l * (BLK * 2))[t];
        smem[t * OUT_PP + 3 + 2 * l]     = v.x;
        smem[t * OUT_PP + 3 + 2 * l + 1] = v.y;
    }
    __syncthreads();

    const size_t gbase = (size_t)c * (BLK * OUT_PP);
    const long long remain = (long long)NPTS * OUT_PP - (long long)gbase;
    const int n4 = (int)((remain < (long long)(BLK * OUT_PP) ? remain : (long long)(BLK * OUT_PP)) / 4);
    const vfloat4* __restrict__ s4 = reinterpret_cast<const vfloat4*>(smem);
    vfloat4* __restrict__ o4 = reinterpret_cast<vfloat4*>(out + gbase);
    for (int j = t; j < n4; j += BLK)
        __builtin_nontemporal_store(s4[j], o4 + j);
}

// ---------------- Fallback (point-major single kernel) ----------------

__global__ __launch_bounds__(BLK) void hashgrid_fused(
    const float* __restrict__ x,
    const float* __restrict__ tables,
    float* __restrict__ out)
{
    __shared__ float smem[BLK * OUT_PP];

    const int t = threadIdx.x;
    const int i = blockIdx.x * BLK + t;
    const bool active = (i < NPTS);

    float px = 0.f, py = 0.f, pz = 0.f;
    if (active) {
        px = x[3 * i + 0];
        py = x[3 * i + 1];
        pz = x[3 * i + 2];
    }
    smem[t * OUT_PP + 0] = px;
    smem[t * OUT_PP + 1] = py;
    smem[t * OUT_PP + 2] = pz;

    float f0, f1;
    #pragma unroll
    for (int l = 0; l < NLEV; ++l) {
        do_level_dispatch(l, px, py, pz, tables, f0, f1);
        smem[t * OUT_PP + 3 + 2 * l]     = f0;
        smem[t * OUT_PP + 3 + 2 * l + 1] = f1;
    }

    __syncthreads();

    const size_t gbase = (size_t)blockIdx.x * (BLK * OUT_PP);
    const long long remain = (long long)NPTS * OUT_PP - (long long)gbase;
    const int n4 = (int)((remain < (long long)(BLK * OUT_PP) ? remain : (long long)(BLK * OUT_PP)) / 4);
    const float4* __restrict__ s4 = reinterpret_cast<const float4*>(smem);
    float4* __restrict__ o4 = reinterpret_cast<float4*>(out + gbase);
    for (int j = t; j < n4; j += BLK) o4[j] = s4[j];
}

extern "C" void kernel_launch(void* const* d_in, const int* in_sizes, int n_in,
                              void* d_out, int out_size, void* d_ws, size_t ws_size,
                              hipStream_t stream)
{
    const float* x      = (const float*)d_in[0];   // (1e6, 3) f32
    const float* tables = (const float*)d_in[1];   // (16, 2^19, 2) f32
    float* out          = (float*)d_out;           // (1e6, 35) f32

    const size_t ws_needed = (size_t)CHUNKS * WS_CHUNK * sizeof(float);  // ~128 MB

    if (ws_size >= ws_needed) {
        float* ws = (float*)d_ws;
        hashgrid_pass1<<<NLEV * CHUNKS, BLK, 0, stream>>>(x, tables, ws);
        hashgrid_pass2<<<CHUNKS, BLK, 0, stream>>>(x, ws, out);
    } else {
        hashgrid_fused<<<CHUNKS, BLK, 0, stream>>>(x, tables, out);
    }
}